// Round 13
// baseline (854.296 us; speedup 1.0000x reference)
//
#include <hip/hip_runtime.h>

#define NN 65536
#define NE 524288
#define SLOPE 0.01f

typedef unsigned short us;
typedef __attribute__((ext_vector_type(8))) short short8;
typedef __attribute__((ext_vector_type(4))) float f32x4;

__device__ __forceinline__ float leaky(float v) { return v >= 0.f ? v : SLOPE * v; }
__device__ __forceinline__ float b2f(us u) { return __uint_as_float(((unsigned)u) << 16); }
__device__ __forceinline__ us f2b(float f) {
  unsigned u = __float_as_uint(f);
  u += 0x7fffu + ((u >> 16) & 1u);
  return (us)(u >> 16);
}
__device__ __forceinline__ void split2(float v, us& hi, us& lo) {
  hi = f2b(v);
  lo = f2b(v - b2f(hi));
}

__device__ __forceinline__ void gload16(const void* g, void* l) {
  __builtin_amdgcn_global_load_lds(
      (const __attribute__((address_space(1))) unsigned int*)g,
      (__attribute__((address_space(3))) unsigned int*)l, 16, 0, 0);
}

// ---------------- graph preprocessing ----------------
__global__ void zero_ints(int* __restrict__ p, int n) {
  int i = blockIdx.x * blockDim.x + threadIdx.x;
  if (i < n) p[i] = 0;
}

__global__ void deg_count(const int* __restrict__ src, const int* __restrict__ dst,
                          int* __restrict__ cout, int* __restrict__ cin) {
  int e = blockIdx.x * blockDim.x + threadIdx.x;
  if (e < NE) {
    atomicAdd(&cout[src[e]], 1);
    atomicAdd(&cin[dst[e]], 1);
  }
}

__global__ void rs_kernel(const int* __restrict__ cout, const int* __restrict__ cin,
                          float* __restrict__ rs_out, float* __restrict__ rs_in) {
  int n = blockIdx.x * blockDim.x + threadIdx.x;
  if (n < NN) {
    rs_out[n] = rsqrtf((float)(cout[n] > 0 ? cout[n] : 1));
    rs_in[n]  = rsqrtf((float)(cin[n]  > 0 ? cin[n]  : 1));
  }
}

__global__ __launch_bounds__(1024) void scan_kernel(const int* __restrict__ cnt,
                                                    int* __restrict__ row_ptr) {
  __shared__ int part[1024];
  int t = threadIdx.x;
  int base = t * 64;
  int s = 0;
  for (int i = 0; i < 64; ++i) s += cnt[base + i];
  part[t] = s;
  __syncthreads();
  for (int d = 1; d < 1024; d <<= 1) {
    int v = (t >= d) ? part[t - d] : 0;
    __syncthreads();
    part[t] += v;
    __syncthreads();
  }
  int run = part[t] - s;
  for (int i = 0; i < 64; ++i) { row_ptr[base + i] = run; run += cnt[base + i]; }
  if (t == 1023) row_ptr[NN] = run;
}

__global__ void csr_fill(const int* __restrict__ src, const int* __restrict__ dst,
                         const int* __restrict__ row_ptr, int* __restrict__ cursor,
                         int* __restrict__ csr) {
  int e = blockIdx.x * blockDim.x + threadIdx.x;
  if (e < NE) {
    int d = dst[e];
    int pos = atomicAdd(&cursor[d], 1);
    csr[row_ptr[d] + pos] = src[e];
  }
}

// x [512][128c][128v] -> h0 planes [65536 node][128 c] (hi/lo bf16)
__global__ __launch_bounds__(256) void transpose_x(const float* __restrict__ x,
                                                   us* __restrict__ h0h,
                                                   us* __restrict__ h0l) {
  __shared__ float tile[128][68];
  int s  = blockIdx.x >> 1;
  int vh = (blockIdx.x & 1) * 64;
  const float* xs = x + (size_t)s * 16384;
  int t = threadIdx.x;
  int v4 = t & 15, c0 = t >> 4;
  for (int p = 0; p < 8; ++p) {
    int c = c0 + p * 16;
    float4 val = *(const float4*)(xs + (size_t)c * 128 + vh + v4 * 4);
    *(float4*)&tile[c][v4 * 4] = val;
  }
  __syncthreads();
  int c4 = t & 31, v0 = t >> 5;
  for (int p = 0; p < 8; ++p) {
    int v = v0 + p * 8;
    float o[4];
    o[0] = tile[c4 * 4 + 0][v];
    o[1] = tile[c4 * 4 + 1][v];
    o[2] = tile[c4 * 4 + 2][v];
    o[3] = tile[c4 * 4 + 3][v];
    us hh[4], ll[4];
#pragma unroll
    for (int j = 0; j < 4; ++j) split2(o[j], hh[j], ll[j]);
    size_t off = (size_t)(s * 128 + vh + v) * 128 + c4 * 4;
    uint2 wh = make_uint2((unsigned)hh[0] | ((unsigned)hh[1] << 16),
                          (unsigned)hh[2] | ((unsigned)hh[3] << 16));
    uint2 wl = make_uint2((unsigned)ll[0] | ((unsigned)ll[1] << 16),
                          (unsigned)ll[2] | ((unsigned)ll[3] << 16));
    *(uint2*)(h0h + off) = wh;
    *(uint2*)(h0l + off) = wl;
  }
}

// weight split, fragment-major layout B'[n][k] (src row-major [n][ld], cols koff..)
__global__ void wsplit(const float* __restrict__ src, us* __restrict__ bh,
                       us* __restrict__ bl, int N, int K, int ld, int koff) {
  int idx = blockIdx.x * 256 + threadIdx.x;
  if (idx >= N * K) return;
  int n = idx / K, k = idx - n * K;
  float v = src[(size_t)n * ld + koff + k];
  us hi, lo; split2(v, hi, lo);
  bh[idx] = hi; bl[idx] = lo;
}

// weight split transposed: B'[n][k] = src[k*ld + n]   (conv weights W[k_in][n_out])
__global__ void wsplit_t(const float* __restrict__ src, us* __restrict__ bh,
                         us* __restrict__ bl, int N, int K, int ld) {
  int idx = blockIdx.x * 256 + threadIdx.x;
  if (idx >= N * K) return;
  int n = idx / K, k = idx - n * K;
  float v = src[(size_t)k * ld + n];
  us hi, lo; split2(v, hi, lo);
  bh[idx] = hi; bl[idx] = lo;
}

// aggregate: 2 nodes/wave, 16 B/lane, 4-edge unroll.
__global__ __launch_bounds__(256) void aggregate(
    const us* __restrict__ hh, const us* __restrict__ hl, int lda,
    const int* __restrict__ row_ptr, const int* __restrict__ csr,
    const float* __restrict__ rs_out, const float* __restrict__ rs_in,
    us* __restrict__ aggh, us* __restrict__ aggl) {
  const int lane = threadIdx.x & 63;
  const int wid = threadIdx.x >> 6;
  const int half = (lane >> 5) & 1;
  const int n = blockIdx.x * 8 + wid * 2 + half;
  const bool lop = (lane & 31) >= 16;
  const int c16 = lane & 15;
  const us* base = (lop ? hl : hh) + (size_t)c16 * 8;
  const int b = row_ptr[n], e = row_ptr[n + 1];
  float a[8];
#pragma unroll
  for (int j = 0; j < 8; ++j) a[j] = 0.f;
  int i = b;
  for (; i + 4 <= e; i += 4) {
    int s0 = csr[i], s1 = csr[i + 1], s2 = csr[i + 2], s3 = csr[i + 3];
    uint4 v0 = *(const uint4*)(base + (size_t)s0 * lda);
    uint4 v1 = *(const uint4*)(base + (size_t)s1 * lda);
    uint4 v2 = *(const uint4*)(base + (size_t)s2 * lda);
    uint4 v3 = *(const uint4*)(base + (size_t)s3 * lda);
    float w0 = rs_out[s0], w1 = rs_out[s1], w2 = rs_out[s2], w3 = rs_out[s3];
    a[0] = fmaf(w0, __uint_as_float(v0.x << 16), a[0]);
    a[1] = fmaf(w0, __uint_as_float(v0.x & 0xffff0000u), a[1]);
    a[2] = fmaf(w0, __uint_as_float(v0.y << 16), a[2]);
    a[3] = fmaf(w0, __uint_as_float(v0.y & 0xffff0000u), a[3]);
    a[4] = fmaf(w0, __uint_as_float(v0.z << 16), a[4]);
    a[5] = fmaf(w0, __uint_as_float(v0.z & 0xffff0000u), a[5]);
    a[6] = fmaf(w0, __uint_as_float(v0.w << 16), a[6]);
    a[7] = fmaf(w0, __uint_as_float(v0.w & 0xffff0000u), a[7]);
    a[0] = fmaf(w1, __uint_as_float(v1.x << 16), a[0]);
    a[1] = fmaf(w1, __uint_as_float(v1.x & 0xffff0000u), a[1]);
    a[2] = fmaf(w1, __uint_as_float(v1.y << 16), a[2]);
    a[3] = fmaf(w1, __uint_as_float(v1.y & 0xffff0000u), a[3]);
    a[4] = fmaf(w1, __uint_as_float(v1.z << 16), a[4]);
    a[5] = fmaf(w1, __uint_as_float(v1.z & 0xffff0000u), a[5]);
    a[6] = fmaf(w1, __uint_as_float(v1.w << 16), a[6]);
    a[7] = fmaf(w1, __uint_as_float(v1.w & 0xffff0000u), a[7]);
    a[0] = fmaf(w2, __uint_as_float(v2.x << 16), a[0]);
    a[1] = fmaf(w2, __uint_as_float(v2.x & 0xffff0000u), a[1]);
    a[2] = fmaf(w2, __uint_as_float(v2.y << 16), a[2]);
    a[3] = fmaf(w2, __uint_as_float(v2.y & 0xffff0000u), a[3]);
    a[4] = fmaf(w2, __uint_as_float(v2.z << 16), a[4]);
    a[5] = fmaf(w2, __uint_as_float(v2.z & 0xffff0000u), a[5]);
    a[6] = fmaf(w2, __uint_as_float(v2.w << 16), a[6]);
    a[7] = fmaf(w2, __uint_as_float(v2.w & 0xffff0000u), a[7]);
    a[0] = fmaf(w3, __uint_as_float(v3.x << 16), a[0]);
    a[1] = fmaf(w3, __uint_as_float(v3.x & 0xffff0000u), a[1]);
    a[2] = fmaf(w3, __uint_as_float(v3.y << 16), a[2]);
    a[3] = fmaf(w3, __uint_as_float(v3.y & 0xffff0000u), a[3]);
    a[4] = fmaf(w3, __uint_as_float(v3.z << 16), a[4]);
    a[5] = fmaf(w3, __uint_as_float(v3.z & 0xffff0000u), a[5]);
    a[6] = fmaf(w3, __uint_as_float(v3.w << 16), a[6]);
    a[7] = fmaf(w3, __uint_as_float(v3.w & 0xffff0000u), a[7]);
  }
  for (; i < e; ++i) {
    int s0 = csr[i];
    uint4 v0 = *(const uint4*)(base + (size_t)s0 * lda);
    float w0 = rs_out[s0];
    a[0] = fmaf(w0, __uint_as_float(v0.x << 16), a[0]);
    a[1] = fmaf(w0, __uint_as_float(v0.x & 0xffff0000u), a[1]);
    a[2] = fmaf(w0, __uint_as_float(v0.y << 16), a[2]);
    a[3] = fmaf(w0, __uint_as_float(v0.y & 0xffff0000u), a[3]);
    a[4] = fmaf(w0, __uint_as_float(v0.z << 16), a[4]);
    a[5] = fmaf(w0, __uint_as_float(v0.z & 0xffff0000u), a[5]);
    a[6] = fmaf(w0, __uint_as_float(v0.w << 16), a[6]);
    a[7] = fmaf(w0, __uint_as_float(v0.w & 0xffff0000u), a[7]);
  }
#pragma unroll
  for (int j = 0; j < 8; ++j) a[j] += __shfl_xor(a[j], 16);
  const float ri = rs_in[n];
  us h8[8], l8[8];
#pragma unroll
  for (int j = 0; j < 8; ++j) split2(a[j] * ri, h8[j], l8[j]);
  size_t o = (size_t)n * 128 + (size_t)c16 * 8;
  if (!lop) {
    uint4 w = make_uint4((unsigned)h8[0] | ((unsigned)h8[1] << 16),
                         (unsigned)h8[2] | ((unsigned)h8[3] << 16),
                         (unsigned)h8[4] | ((unsigned)h8[5] << 16),
                         (unsigned)h8[6] | ((unsigned)h8[7] << 16));
    *(uint4*)(aggh + o) = w;
  } else {
    uint4 w = make_uint4((unsigned)l8[0] | ((unsigned)l8[1] << 16),
                         (unsigned)l8[2] | ((unsigned)l8[3] << 16),
                         (unsigned)l8[4] | ((unsigned)l8[5] << 16),
                         (unsigned)l8[6] | ((unsigned)l8[7] << 16));
    *(uint4*)(aggl + o) = w;
  }
}

// ---------------- 1024-thread (16-wave, 4Mx4N) free-run split-bf16 MFMA GEMM ----------------
// BM=256. Wave tile 64 x (FN*16). Same linear-chunk LDS + counted-vmcnt dbuf as R9/R12,
// but 4 waves/SIMD for latency hiding (R12's 2/SIMD pinned MfmaUtil at 22%).
// MODE 1: conv res (+prev; colOff=0 -> head via prev=null trick NOT used; MODE 0 head)
// MODE 0: conv head  MODE 2: fusion+max  MODE 3: p1 (+gcon)
template<int KTOT, int BN, int MODE>
__global__ __launch_bounds__(1024) void mgemm16(
    const us* __restrict__ Ah, const us* __restrict__ Al, int lda,
    const us* __restrict__ Bh, const us* __restrict__ Bl,
    const float* __restrict__ bias,
    float* __restrict__ outf, us* __restrict__ outh, us* __restrict__ outl,
    int ldo, int colOff,
    const us* __restrict__ prevh, const us* __restrict__ prevl,
    const float* __restrict__ gcon) {
  constexpr int FN  = BN / 64;            // 4 (BN=256) or 2 (BN=128)
  constexpr int NT  = KTOT / 32;
  constexpr int LBN = (BN == 256) ? 8 : 7;
  constexpr int CHT = 2048 + BN * 8;
  constexpr int LPT = CHT / 1024;         // 4 or 3

  __shared__ __align__(16) us L[2][CHT * 8];

  const int t = threadIdx.x;
  const int mbase = blockIdx.x * 256;

  const us* gp[LPT];
#pragma unroll
  for (int i = 0; i < LPT; ++i) {
    int id = i * 1024 + t;
    if (id < 1024) {
      int row = id & 255, kb = id >> 8;
      gp[i] = Ah + (size_t)(mbase + row) * lda + kb * 8;
    } else if (id < 2048) {
      int c = id - 1024, row = c & 255, kb = c >> 8;
      gp[i] = Al + (size_t)(mbase + row) * lda + kb * 8;
    } else if (id < 2048 + BN * 4) {
      int c = id - 2048, row = c & (BN - 1), kb = c >> LBN;
      gp[i] = Bh + (size_t)row * KTOT + kb * 8;
    } else {
      int c = id - 2048 - BN * 4, row = c & (BN - 1), kb = c >> LBN;
      gp[i] = Bl + (size_t)row * KTOT + kb * 8;
    }
  }

  const int lane = t & 63, wvi = t >> 6;  // 16 waves
  const int wm = wvi & 3, wn = wvi >> 2;  // 4M x 4N
  const int l15 = lane & 15, lkb = lane >> 4;
  const int wrow = wm * 64;

  f32x4 acc[4][FN];
#pragma unroll
  for (int i = 0; i < 4; ++i)
#pragma unroll
    for (int j = 0; j < FN; ++j)
#pragma unroll
      for (int e = 0; e < 4; ++e) acc[i][j][e] = 0.f;

  auto stage = [&](us* Lb, int k0) {
#pragma unroll
    for (int i = 0; i < LPT; ++i)
      gload16(gp[i] + k0, Lb + (size_t)(i * 1024 + t) * 8);
  };
  auto waitL = [&]() {
    if constexpr (LPT == 4) asm volatile("s_waitcnt vmcnt(4)" ::: "memory");
    else                    asm volatile("s_waitcnt vmcnt(3)" ::: "memory");
    __builtin_amdgcn_sched_barrier(0);
  };
  auto wait0 = [&]() {
    asm volatile("s_waitcnt vmcnt(0)" ::: "memory");
    __builtin_amdgcn_sched_barrier(0);
  };
  auto bar = [&]() {
    __builtin_amdgcn_s_barrier();
    __builtin_amdgcn_sched_barrier(0);
  };
  auto ktile = [&](const us* Lb) {
    short8 bh[FN], bl[FN];
#pragma unroll
    for (int fn = 0; fn < FN; ++fn) {
      const int bcol = wn * (FN * 16) + fn * 16 + l15;
      bh[fn] = *(const short8*)(Lb + ((size_t)(2048 + lkb * BN + bcol)) * 8);
      bl[fn] = *(const short8*)(Lb + ((size_t)(2048 + BN * 4 + lkb * BN + bcol)) * 8);
    }
#pragma unroll
    for (int p = 0; p < 2; ++p) {
      short8 ah[2], al[2];
#pragma unroll
      for (int f = 0; f < 2; ++f) {
        const int arow = wrow + (p * 2 + f) * 16 + l15;
        ah[f] = *(const short8*)(Lb + ((size_t)(lkb * 256 + arow)) * 8);
        al[f] = *(const short8*)(Lb + ((size_t)(1024 + lkb * 256 + arow)) * 8);
      }
      __builtin_amdgcn_s_setprio(1);
#pragma unroll
      for (int f = 0; f < 2; ++f)
#pragma unroll
        for (int fn = 0; fn < FN; ++fn)
          acc[p * 2 + f][fn] =
              __builtin_amdgcn_mfma_f32_16x16x32_bf16(ah[f], bh[fn], acc[p * 2 + f][fn], 0, 0, 0);
#pragma unroll
      for (int f = 0; f < 2; ++f)
#pragma unroll
        for (int fn = 0; fn < FN; ++fn)
          acc[p * 2 + f][fn] =
              __builtin_amdgcn_mfma_f32_16x16x32_bf16(al[f], bh[fn], acc[p * 2 + f][fn], 0, 0, 0);
#pragma unroll
      for (int f = 0; f < 2; ++f)
#pragma unroll
        for (int fn = 0; fn < FN; ++fn)
          acc[p * 2 + f][fn] =
              __builtin_amdgcn_mfma_f32_16x16x32_bf16(ah[f], bl[fn], acc[p * 2 + f][fn], 0, 0, 0);
      __builtin_amdgcn_s_setprio(0);
      __builtin_amdgcn_sched_barrier(0);
    }
  };

  stage(L[0], 0);
  if (NT > 1) stage(L[1], 32);
#pragma unroll 1
  for (int kt = 0; kt < NT; kt += 2) {
    waitL();
    bar();
    ktile(L[0]);
    bar();
    if (kt + 2 < NT) stage(L[0], (kt + 2) * 32);
    if (kt + 3 < NT) waitL(); else wait0();
    bar();
    ktile(L[1]);
    bar();
    if (kt + 3 < NT) stage(L[1], (kt + 3) * 32);
  }

  // C/D: col = lane&15, row = (lane>>4)*4 + reg
  if constexpr (MODE == 0 || MODE == 1 || MODE == 3) {
    const float* gc = (MODE == 3) ? (gcon + (size_t)(blockIdx.x * 2 + (wm >> 1)) * 256) : nullptr;
#pragma unroll
    for (int fm = 0; fm < 4; ++fm)
#pragma unroll
      for (int fn = 0; fn < FN; ++fn) {
        const int col = wn * (FN * 16) + fn * 16 + l15;
        float bb = bias[col];
        if constexpr (MODE == 3) bb += gc[col];
#pragma unroll
        for (int r = 0; r < 4; ++r) {
          const int row = mbase + wrow + fm * 16 + lkb * 4 + r;
          float v = leaky(acc[fm][fn][r] + bb);
          const size_t off = (size_t)row * ldo + colOff + col;
          if constexpr (MODE == 1) v += b2f(prevh[off - 128]) + b2f(prevl[off - 128]);
          us hi, lo; split2(v, hi, lo);
          outh[off] = hi;
          outl[off] = lo;
        }
      }
  } else if constexpr (MODE == 2) {
    __shared__ float red[4][256];
#pragma unroll
    for (int fn = 0; fn < FN; ++fn) {
      float m = acc[0][fn][0];
#pragma unroll
      for (int fm = 0; fm < 4; ++fm)
#pragma unroll
        for (int r = 0; r < 4; ++r) m = fmaxf(m, acc[fm][fn][r]);
      m = fmaxf(m, __shfl_xor(m, 16));
      m = fmaxf(m, __shfl_xor(m, 32));
      if (lane < 16) red[wm][wn * (FN * 16) + fn * 16 + l15] = m;
    }
    __syncthreads();
    if (t < 512) {
      int s = t >> 8, col = t & 255;
      float m = fmaxf(red[2 * s][col], red[2 * s + 1][col]);
      outf[(size_t)(blockIdx.x * 2 + s) * 256 + col] = m + bias[col];
    }
  }
}

// ---------------- 512-thread GEMM (kept for p2 only) ----------------
template<int KTOT, int BN, int WM, int PH, int MODE>
__global__ __launch_bounds__(512) void mgemm8(
    const us* __restrict__ Ah, const us* __restrict__ Al, int lda,
    const us* __restrict__ Bh, const us* __restrict__ Bl,
    const float* __restrict__ bias,
    float* __restrict__ outf, us* __restrict__ outh, us* __restrict__ outl,
    int ldo, int colOff) {
  constexpr int WN  = 8 / WM;
  constexpr int FM  = 16 / WM;
  constexpr int FMP = FM / PH;
  constexpr int NT  = KTOT / 32;
  constexpr int LBN = (BN == 256) ? 8 : ((BN == 128) ? 7 : 6);
  constexpr int CHT = 2048 + BN * 8;
  constexpr int LPT = CHT / 512;

  __shared__ __align__(16) us L[2][CHT * 8];

  const int t = threadIdx.x;
  const int mbase = blockIdx.x * 256;

  const us* gp[LPT];
#pragma unroll
  for (int i = 0; i < LPT; ++i) {
    int id = i * 512 + t;
    if (id < 1024) {
      int row = id & 255, kb = id >> 8;
      gp[i] = Ah + (size_t)(mbase + row) * lda + kb * 8;
    } else if (id < 2048) {
      int c = id - 1024, row = c & 255, kb = c >> 8;
      gp[i] = Al + (size_t)(mbase + row) * lda + kb * 8;
    } else if (id < 2048 + BN * 4) {
      int c = id - 2048, row = c & (BN - 1), kb = c >> LBN;
      gp[i] = Bh + (size_t)row * KTOT + kb * 8;
    } else {
      int c = id - 2048 - BN * 4, row = c & (BN - 1), kb = c >> LBN;
      gp[i] = Bl + (size_t)row * KTOT + kb * 8;
    }
  }

  const int lane = t & 63, wvi = t >> 6;
  const int wm = wvi & (WM - 1), wn = wvi / WM;
  const int l15 = lane & 15, lkb = lane >> 4;
  const int wrow = wm * (256 / WM);

  f32x4 acc[FM][4];
#pragma unroll
  for (int i = 0; i < FM; ++i)
#pragma unroll
    for (int j = 0; j < 4; ++j)
#pragma unroll
      for (int e = 0; e < 4; ++e) acc[i][j][e] = 0.f;

  auto stage = [&](us* Lb, int k0) {
#pragma unroll
    for (int i = 0; i < LPT; ++i)
      gload16(gp[i] + k0, Lb + (size_t)(i * 512 + t) * 8);
  };
  auto waitL = [&]() {
    if constexpr (LPT == 8)      asm volatile("s_waitcnt vmcnt(8)" ::: "memory");
    else if constexpr (LPT == 6) asm volatile("s_waitcnt vmcnt(6)" ::: "memory");
    else                         asm volatile("s_waitcnt vmcnt(5)" ::: "memory");
    __builtin_amdgcn_sched_barrier(0);
  };
  auto wait0 = [&]() {
    asm volatile("s_waitcnt vmcnt(0)" ::: "memory");
    __builtin_amdgcn_sched_barrier(0);
  };
  auto bar = [&]() {
    __builtin_amdgcn_s_barrier();
    __builtin_amdgcn_sched_barrier(0);
  };
  auto ktile = [&](const us* Lb) {
    short8 bh[4], bl[4];
#pragma unroll
    for (int fn = 0; fn < 4; ++fn) {
      const int bcol = wn * 64 + fn * 16 + l15;
      bh[fn] = *(const short8*)(Lb + ((size_t)(2048 + lkb * BN + bcol)) * 8);
      bl[fn] = *(const short8*)(Lb + ((size_t)(2048 + BN * 4 + lkb * BN + bcol)) * 8);
    }
#pragma unroll
    for (int p = 0; p < PH; ++p) {
      short8 ah[FMP], al[FMP];
#pragma unroll
      for (int f = 0; f < FMP; ++f) {
        const int arow = wrow + (p * FMP + f) * 16 + l15;
        ah[f] = *(const short8*)(Lb + ((size_t)(lkb * 256 + arow)) * 8);
        al[f] = *(const short8*)(Lb + ((size_t)(1024 + lkb * 256 + arow)) * 8);
      }
      __builtin_amdgcn_s_setprio(1);
#pragma unroll
      for (int f = 0; f < FMP; ++f)
#pragma unroll
        for (int fn = 0; fn < 4; ++fn)
          acc[p * FMP + f][fn] =
              __builtin_amdgcn_mfma_f32_16x16x32_bf16(ah[f], bh[fn], acc[p * FMP + f][fn], 0, 0, 0);
#pragma unroll
      for (int f = 0; f < FMP; ++f)
#pragma unroll
        for (int fn = 0; fn < 4; ++fn)
          acc[p * FMP + f][fn] =
              __builtin_amdgcn_mfma_f32_16x16x32_bf16(al[f], bh[fn], acc[p * FMP + f][fn], 0, 0, 0);
#pragma unroll
      for (int f = 0; f < FMP; ++f)
#pragma unroll
        for (int fn = 0; fn < 4; ++fn)
          acc[p * FMP + f][fn] =
              __builtin_amdgcn_mfma_f32_16x16x32_bf16(ah[f], bl[fn], acc[p * FMP + f][fn], 0, 0, 0);
      __builtin_amdgcn_s_setprio(0);
      __builtin_amdgcn_sched_barrier(0);
    }
  };

  stage(L[0], 0);
  if (NT > 1) stage(L[1], 32);
#pragma unroll 1
  for (int kt = 0; kt < NT; kt += 2) {
    waitL();
    bar();
    ktile(L[0]);
    bar();
    if (kt + 2 < NT) stage(L[0], (kt + 2) * 32);
    if (kt + 3 < NT) waitL(); else wait0();
    bar();
    ktile(L[1]);
    bar();
    if (kt + 3 < NT) stage(L[1], (kt + 3) * 32);
  }

  // MODE 4: p2, BN=64, WN=1
#pragma unroll
  for (int fm = 0; fm < FM; ++fm)
#pragma unroll
    for (int fn = 0; fn < 4; ++fn) {
      const int col = fn * 16 + l15;
      const float bb = bias[col];
#pragma unroll
      for (int r = 0; r < 4; ++r) {
        const int row = mbase + wrow + fm * 16 + lkb * 4 + r;
        outf[(size_t)row * 64 + col] = leaky(acc[fm][fn][r] + bb);
      }
    }
}

// gcon[s][o] = sum_{c<256} gmax[s][c] * W_p1[o][c]
__global__ void gcon_kernel(const float* __restrict__ gmax, const float* __restrict__ Wp1,
                            float* __restrict__ gcon) {
  __shared__ float g[256];
  int s = blockIdx.x, o = threadIdx.x;
  g[o] = gmax[(size_t)s * 256 + o];
  __syncthreads();
  float acc = 0.f;
  const float* wr = Wp1 + (size_t)o * 768;
#pragma unroll 8
  for (int c = 0; c < 256; ++c) acc += g[c] * wr[c];
  gcon[(size_t)s * 256 + o] = acc;
}

// out[s][o][v] = b3[o] + sum_{j<64} y2[n][j] * Wp3[o][j],  n = s*128+v
__global__ void p3_kernel(const float* __restrict__ y2, const float* __restrict__ W,
                          const float* __restrict__ b, float* __restrict__ out) {
  __shared__ float w0[64], w1[64];
  int t = threadIdx.x;
  if (t < 64) { w0[t] = W[t]; w1[t] = W[64 + t]; }
  __syncthreads();
  int n = blockIdx.x * 256 + t;
  const float* row = y2 + (size_t)n * 64;
  float a0 = b[0], a1 = b[1];
#pragma unroll
  for (int j = 0; j < 64; j += 4) {
    float4 v = *(const float4*)(row + j);
    a0 += v.x * w0[j] + v.y * w0[j + 1] + v.z * w0[j + 2] + v.w * w0[j + 3];
    a1 += v.x * w1[j] + v.y * w1[j + 1] + v.z * w1[j + 2] + v.w * w1[j + 3];
  }
  int s = n >> 7, vv = n & 127;
  out[((size_t)s * 2 + 0) * 128 + vv] = a0;
  out[((size_t)s * 2 + 1) * 128 + vv] = a1;
}

extern "C" void kernel_launch(void* const* d_in, const int* in_sizes, int n_in,
                              void* d_out, int out_size, void* d_ws, size_t ws_size,
                              hipStream_t stream) {
  const float* x        = (const float*)d_in[0];
  const int*   esrc     = (const int*)d_in[1];
  const int*   edst     = (const int*)d_in[2];
  const float* W_head   = (const float*)d_in[3];
  const float* b_head   = (const float*)d_in[4];
  const float* W_res[3] = {(const float*)d_in[5], (const float*)d_in[7], (const float*)d_in[9]};
  const float* b_res[3] = {(const float*)d_in[6], (const float*)d_in[8], (const float*)d_in[10]};
  const float* W_fusion = (const float*)d_in[11];
  const float* b_fusion = (const float*)d_in[12];
  const float* W_p1     = (const float*)d_in[13];
  const float* b_p1     = (const float*)d_in[14];
  const float* W_p2     = (const float*)d_in[15];
  const float* b_p2     = (const float*)d_in[16];
  const float* W_p3     = (const float*)d_in[17];
  const float* b_p3     = (const float*)d_in[18];
  float* outp = (float*)d_out;

  char* w = (char*)d_ws;
  size_t off = 0;
  auto alloc = [&](size_t bytes) { char* p = w + off; off += (bytes + 255) & ~(size_t)255; return p; };

  us* states_h = (us*)alloc((size_t)NN * 512 * 2);
  us* states_l = (us*)alloc((size_t)NN * 512 * 2);
  char* regionA = alloc((size_t)NN * 128 * 2 * 4);
  us* h0h  = (us*)regionA;
  us* h0l  = (us*)(regionA + (size_t)NN * 128 * 2);
  us* aggh = (us*)(regionA + (size_t)NN * 128 * 4);
  us* aggl = (us*)(regionA + (size_t)NN * 128 * 6);
  us* y1h  = (us*)regionA;
  us* y1l  = (us*)(regionA + (size_t)NN * 256 * 2);
  float* y2 = (float*)states_h;

  float* gmax   = (float*)alloc(512 * 256 * 4);
  float* gcon   = (float*)alloc(512 * 256 * 4);
  float* rs_out = (float*)alloc((size_t)NN * 4);
  float* rs_in  = (float*)alloc((size_t)NN * 4);
  us* cWh[4]; us* cWl[4];
  for (int l = 0; l < 4; ++l) { cWh[l] = (us*)alloc(128 * 128 * 2); cWl[l] = (us*)alloc(128 * 128 * 2); }
  us* fWh  = (us*)alloc(256 * 512 * 2);
  us* fWl  = (us*)alloc(256 * 512 * 2);
  us* p1Wh = (us*)alloc(256 * 512 * 2);
  us* p1Wl = (us*)alloc(256 * 512 * 2);
  us* p2Wh = (us*)alloc(64 * 256 * 2);
  us* p2Wl = (us*)alloc(64 * 256 * 2);
  int* cnt_out = (int*)alloc((size_t)NN * 4);
  int* cnt_in  = (int*)alloc((size_t)NN * 4);
  int* cursor  = (int*)alloc((size_t)NN * 4);
  int* row_ptr = (int*)alloc(((size_t)NN + 1) * 4);
  int* csr     = (int*)alloc((size_t)NE * 4);

  zero_ints<<<(3 * NN + 255) / 256, 256, 0, stream>>>(cnt_out, 3 * NN);
  deg_count<<<NE / 256, 256, 0, stream>>>(esrc, edst, cnt_out, cnt_in);
  rs_kernel<<<NN / 256, 256, 0, stream>>>(cnt_out, cnt_in, rs_out, rs_in);
  scan_kernel<<<1, 1024, 0, stream>>>(cnt_in, row_ptr);
  csr_fill<<<NE / 256, 256, 0, stream>>>(esrc, edst, row_ptr, cursor, csr);

  transpose_x<<<1024, 256, 0, stream>>>(x, h0h, h0l);
  const float* cW[4] = {W_head, W_res[0], W_res[1], W_res[2]};
  for (int l = 0; l < 4; ++l)
    wsplit_t<<<64, 256, 0, stream>>>(cW[l], cWh[l], cWl[l], 128, 128, 128);
  wsplit<<<512, 256, 0, stream>>>(W_fusion, fWh, fWl, 256, 512, 512, 0);
  wsplit<<<512, 256, 0, stream>>>(W_p1, p1Wh, p1Wl, 256, 512, 768, 256);
  wsplit<<<64, 256, 0, stream>>>(W_p2, p2Wh, p2Wl, 64, 256, 256, 0);

  const float* cB[4] = {b_head, b_res[0], b_res[1], b_res[2]};
  // layer 1 (head)
  aggregate<<<NN / 8, 256, 0, stream>>>(h0h, h0l, 128, row_ptr, csr, rs_out, rs_in, aggh, aggl);
  mgemm16<128, 128, 0><<<256, 1024, 0, stream>>>(aggh, aggl, 128, cWh[0], cWl[0], cB[0],
                                                 nullptr, states_h, states_l, 512, 0,
                                                 nullptr, nullptr, nullptr);
  // layers 2..4 (residual)
  for (int l = 1; l <= 3; ++l) {
    aggregate<<<NN / 8, 256, 0, stream>>>(states_h + (size_t)(l - 1) * 128,
                                          states_l + (size_t)(l - 1) * 128, 512,
                                          row_ptr, csr, rs_out, rs_in, aggh, aggl);
    mgemm16<128, 128, 1><<<256, 1024, 0, stream>>>(aggh, aggl, 128, cWh[l], cWl[l], cB[l],
                                                   nullptr, states_h, states_l, 512, l * 128,
                                                   states_h, states_l, nullptr);
  }
  // fusion conv + per-slice max -> gmax
  mgemm16<512, 256, 2><<<256, 1024, 0, stream>>>(states_h, states_l, 512, fWh, fWl, b_fusion,
                                                 gmax, nullptr, nullptr, 0, 0,
                                                 nullptr, nullptr, nullptr);
  gcon_kernel<<<512, 256, 0, stream>>>(gmax, W_p1, gcon);
  // p1 -> y1 planes
  mgemm16<512, 256, 3><<<256, 1024, 0, stream>>>(states_h, states_l, 512, p1Wh, p1Wl, b_p1,
                                                 nullptr, y1h, y1l, 256, 0,
                                                 nullptr, nullptr, gcon);
  // p2 -> y2 fp32 [NN][64]
  mgemm8<256, 64, 8, 2, 4><<<256, 512, 0, stream>>>(y1h, y1l, 256, p2Wh, p2Wl, b_p2,
                                                    y2, nullptr, nullptr, 0, 0);
  // p3
  p3_kernel<<<NN / 256, 256, 0, stream>>>(y2, W_p3, b_p3, outp);
}

// Round 14
// 588.142 us; speedup vs baseline: 1.4525x; 1.4525x over previous
//
#include <hip/hip_runtime.h>

#define NN 65536
#define NE 524288
#define SLOPE 0.01f

typedef unsigned short us;
typedef __attribute__((ext_vector_type(8))) short short8;
typedef __attribute__((ext_vector_type(4))) float f32x4;

__device__ __forceinline__ float leaky(float v) { return v >= 0.f ? v : SLOPE * v; }
__device__ __forceinline__ float b2f(us u) { return __uint_as_float(((unsigned)u) << 16); }
__device__ __forceinline__ us f2b(float f) {
  unsigned u = __float_as_uint(f);
  u += 0x7fffu + ((u >> 16) & 1u);
  return (us)(u >> 16);
}
__device__ __forceinline__ void split2(float v, us& hi, us& lo) {
  hi = f2b(v);
  lo = f2b(v - b2f(hi));
}

__device__ __forceinline__ void gload16(const void* g, void* l) {
  __builtin_amdgcn_global_load_lds(
      (const __attribute__((address_space(1))) unsigned int*)g,
      (__attribute__((address_space(3))) unsigned int*)l, 16, 0, 0);
}

// ---------------- graph preprocessing ----------------
__global__ void zero_ints(int* __restrict__ p, int n) {
  int i = blockIdx.x * blockDim.x + threadIdx.x;
  if (i < n) p[i] = 0;
}

__global__ void deg_count(const int* __restrict__ src, const int* __restrict__ dst,
                          int* __restrict__ cout, int* __restrict__ cin) {
  int e = blockIdx.x * blockDim.x + threadIdx.x;
  if (e < NE) {
    atomicAdd(&cout[src[e]], 1);
    atomicAdd(&cin[dst[e]], 1);
  }
}

__global__ void rs_kernel(const int* __restrict__ cout, const int* __restrict__ cin,
                          float* __restrict__ rs_out, float* __restrict__ rs_in) {
  int n = blockIdx.x * blockDim.x + threadIdx.x;
  if (n < NN) {
    rs_out[n] = rsqrtf((float)(cout[n] > 0 ? cout[n] : 1));
    rs_in[n]  = rsqrtf((float)(cin[n]  > 0 ? cin[n]  : 1));
  }
}

__global__ __launch_bounds__(1024) void scan_kernel(const int* __restrict__ cnt,
                                                    int* __restrict__ row_ptr) {
  __shared__ int part[1024];
  int t = threadIdx.x;
  int base = t * 64;
  int s = 0;
  for (int i = 0; i < 64; ++i) s += cnt[base + i];
  part[t] = s;
  __syncthreads();
  for (int d = 1; d < 1024; d <<= 1) {
    int v = (t >= d) ? part[t - d] : 0;
    __syncthreads();
    part[t] += v;
    __syncthreads();
  }
  int run = part[t] - s;
  for (int i = 0; i < 64; ++i) { row_ptr[base + i] = run; run += cnt[base + i]; }
  if (t == 1023) row_ptr[NN] = run;
}

__global__ void csr_fill(const int* __restrict__ src, const int* __restrict__ dst,
                         const int* __restrict__ row_ptr, int* __restrict__ cursor,
                         int* __restrict__ csr) {
  int e = blockIdx.x * blockDim.x + threadIdx.x;
  if (e < NE) {
    int d = dst[e];
    int pos = atomicAdd(&cursor[d], 1);
    csr[row_ptr[d] + pos] = src[e];
  }
}

// x [512][128c][128v] -> h0 planes [65536 node][128 c] (hi/lo bf16)
__global__ __launch_bounds__(256) void transpose_x(const float* __restrict__ x,
                                                   us* __restrict__ h0h,
                                                   us* __restrict__ h0l) {
  __shared__ float tile[128][68];
  int s  = blockIdx.x >> 1;
  int vh = (blockIdx.x & 1) * 64;
  const float* xs = x + (size_t)s * 16384;
  int t = threadIdx.x;
  int v4 = t & 15, c0 = t >> 4;
  for (int p = 0; p < 8; ++p) {
    int c = c0 + p * 16;
    float4 val = *(const float4*)(xs + (size_t)c * 128 + vh + v4 * 4);
    *(float4*)&tile[c][v4 * 4] = val;
  }
  __syncthreads();
  int c4 = t & 31, v0 = t >> 5;
  for (int p = 0; p < 8; ++p) {
    int v = v0 + p * 8;
    float o[4];
    o[0] = tile[c4 * 4 + 0][v];
    o[1] = tile[c4 * 4 + 1][v];
    o[2] = tile[c4 * 4 + 2][v];
    o[3] = tile[c4 * 4 + 3][v];
    us hh[4], ll[4];
#pragma unroll
    for (int j = 0; j < 4; ++j) split2(o[j], hh[j], ll[j]);
    size_t off = (size_t)(s * 128 + vh + v) * 128 + c4 * 4;
    uint2 wh = make_uint2((unsigned)hh[0] | ((unsigned)hh[1] << 16),
                          (unsigned)hh[2] | ((unsigned)hh[3] << 16));
    uint2 wl = make_uint2((unsigned)ll[0] | ((unsigned)ll[1] << 16),
                          (unsigned)ll[2] | ((unsigned)ll[3] << 16));
    *(uint2*)(h0h + off) = wh;
    *(uint2*)(h0l + off) = wl;
  }
}

// weight split, fragment-major layout B'[n][k] (src row-major [n][ld], cols koff..)
__global__ void wsplit(const float* __restrict__ src, us* __restrict__ bh,
                       us* __restrict__ bl, int N, int K, int ld, int koff) {
  int idx = blockIdx.x * 256 + threadIdx.x;
  if (idx >= N * K) return;
  int n = idx / K, k = idx - n * K;
  float v = src[(size_t)n * ld + koff + k];
  us hi, lo; split2(v, hi, lo);
  bh[idx] = hi; bl[idx] = lo;
}

// weight split transposed: B'[n][k] = src[k*ld + n]   (conv weights W[k_in][n_out])
__global__ void wsplit_t(const float* __restrict__ src, us* __restrict__ bh,
                         us* __restrict__ bl, int N, int K, int ld) {
  int idx = blockIdx.x * 256 + threadIdx.x;
  if (idx >= N * K) return;
  int n = idx / K, k = idx - n * K;
  float v = src[(size_t)k * ld + n];
  us hi, lo; split2(v, hi, lo);
  bh[idx] = hi; bl[idx] = lo;
}

// aggregate: 2 nodes/wave, 16 B/lane, 4-edge unroll.
__global__ __launch_bounds__(256) void aggregate(
    const us* __restrict__ hh, const us* __restrict__ hl, int lda,
    const int* __restrict__ row_ptr, const int* __restrict__ csr,
    const float* __restrict__ rs_out, const float* __restrict__ rs_in,
    us* __restrict__ aggh, us* __restrict__ aggl) {
  const int lane = threadIdx.x & 63;
  const int wid = threadIdx.x >> 6;
  const int half = (lane >> 5) & 1;
  const int n = blockIdx.x * 8 + wid * 2 + half;
  const bool lop = (lane & 31) >= 16;
  const int c16 = lane & 15;
  const us* base = (lop ? hl : hh) + (size_t)c16 * 8;
  const int b = row_ptr[n], e = row_ptr[n + 1];
  float a[8];
#pragma unroll
  for (int j = 0; j < 8; ++j) a[j] = 0.f;
  int i = b;
  for (; i + 4 <= e; i += 4) {
    int s0 = csr[i], s1 = csr[i + 1], s2 = csr[i + 2], s3 = csr[i + 3];
    uint4 v0 = *(const uint4*)(base + (size_t)s0 * lda);
    uint4 v1 = *(const uint4*)(base + (size_t)s1 * lda);
    uint4 v2 = *(const uint4*)(base + (size_t)s2 * lda);
    uint4 v3 = *(const uint4*)(base + (size_t)s3 * lda);
    float w0 = rs_out[s0], w1 = rs_out[s1], w2 = rs_out[s2], w3 = rs_out[s3];
    a[0] = fmaf(w0, __uint_as_float(v0.x << 16), a[0]);
    a[1] = fmaf(w0, __uint_as_float(v0.x & 0xffff0000u), a[1]);
    a[2] = fmaf(w0, __uint_as_float(v0.y << 16), a[2]);
    a[3] = fmaf(w0, __uint_as_float(v0.y & 0xffff0000u), a[3]);
    a[4] = fmaf(w0, __uint_as_float(v0.z << 16), a[4]);
    a[5] = fmaf(w0, __uint_as_float(v0.z & 0xffff0000u), a[5]);
    a[6] = fmaf(w0, __uint_as_float(v0.w << 16), a[6]);
    a[7] = fmaf(w0, __uint_as_float(v0.w & 0xffff0000u), a[7]);
    a[0] = fmaf(w1, __uint_as_float(v1.x << 16), a[0]);
    a[1] = fmaf(w1, __uint_as_float(v1.x & 0xffff0000u), a[1]);
    a[2] = fmaf(w1, __uint_as_float(v1.y << 16), a[2]);
    a[3] = fmaf(w1, __uint_as_float(v1.y & 0xffff0000u), a[3]);
    a[4] = fmaf(w1, __uint_as_float(v1.z << 16), a[4]);
    a[5] = fmaf(w1, __uint_as_float(v1.z & 0xffff0000u), a[5]);
    a[6] = fmaf(w1, __uint_as_float(v1.w << 16), a[6]);
    a[7] = fmaf(w1, __uint_as_float(v1.w & 0xffff0000u), a[7]);
    a[0] = fmaf(w2, __uint_as_float(v2.x << 16), a[0]);
    a[1] = fmaf(w2, __uint_as_float(v2.x & 0xffff0000u), a[1]);
    a[2] = fmaf(w2, __uint_as_float(v2.y << 16), a[2]);
    a[3] = fmaf(w2, __uint_as_float(v2.y & 0xffff0000u), a[3]);
    a[4] = fmaf(w2, __uint_as_float(v2.z << 16), a[4]);
    a[5] = fmaf(w2, __uint_as_float(v2.z & 0xffff0000u), a[5]);
    a[6] = fmaf(w2, __uint_as_float(v2.w << 16), a[6]);
    a[7] = fmaf(w2, __uint_as_float(v2.w & 0xffff0000u), a[7]);
    a[0] = fmaf(w3, __uint_as_float(v3.x << 16), a[0]);
    a[1] = fmaf(w3, __uint_as_float(v3.x & 0xffff0000u), a[1]);
    a[2] = fmaf(w3, __uint_as_float(v3.y << 16), a[2]);
    a[3] = fmaf(w3, __uint_as_float(v3.y & 0xffff0000u), a[3]);
    a[4] = fmaf(w3, __uint_as_float(v3.z << 16), a[4]);
    a[5] = fmaf(w3, __uint_as_float(v3.z & 0xffff0000u), a[5]);
    a[6] = fmaf(w3, __uint_as_float(v3.w << 16), a[6]);
    a[7] = fmaf(w3, __uint_as_float(v3.w & 0xffff0000u), a[7]);
  }
  for (; i < e; ++i) {
    int s0 = csr[i];
    uint4 v0 = *(const uint4*)(base + (size_t)s0 * lda);
    float w0 = rs_out[s0];
    a[0] = fmaf(w0, __uint_as_float(v0.x << 16), a[0]);
    a[1] = fmaf(w0, __uint_as_float(v0.x & 0xffff0000u), a[1]);
    a[2] = fmaf(w0, __uint_as_float(v0.y << 16), a[2]);
    a[3] = fmaf(w0, __uint_as_float(v0.y & 0xffff0000u), a[3]);
    a[4] = fmaf(w0, __uint_as_float(v0.z << 16), a[4]);
    a[5] = fmaf(w0, __uint_as_float(v0.z & 0xffff0000u), a[5]);
    a[6] = fmaf(w0, __uint_as_float(v0.w << 16), a[6]);
    a[7] = fmaf(w0, __uint_as_float(v0.w & 0xffff0000u), a[7]);
  }
#pragma unroll
  for (int j = 0; j < 8; ++j) a[j] += __shfl_xor(a[j], 16);
  const float ri = rs_in[n];
  us h8[8], l8[8];
#pragma unroll
  for (int j = 0; j < 8; ++j) split2(a[j] * ri, h8[j], l8[j]);
  size_t o = (size_t)n * 128 + (size_t)c16 * 8;
  if (!lop) {
    uint4 w = make_uint4((unsigned)h8[0] | ((unsigned)h8[1] << 16),
                         (unsigned)h8[2] | ((unsigned)h8[3] << 16),
                         (unsigned)h8[4] | ((unsigned)h8[5] << 16),
                         (unsigned)h8[6] | ((unsigned)h8[7] << 16));
    *(uint4*)(aggh + o) = w;
  } else {
    uint4 w = make_uint4((unsigned)l8[0] | ((unsigned)l8[1] << 16),
                         (unsigned)l8[2] | ((unsigned)l8[3] << 16),
                         (unsigned)l8[4] | ((unsigned)l8[5] << 16),
                         (unsigned)l8[6] | ((unsigned)l8[7] << 16));
    *(uint4*)(aggl + o) = w;
  }
}

// ---------------- 256-row free-run split-bf16 MFMA GEMM (R12 structure) ----------------
// Per K-tile TWO runtime barriers: waitL(counted vmcnt) -> bar(publish) -> free-run
// ktile (sched_barrier-fenced phases) -> bar(readers done) -> burst restage.
// MODE 0: conv head  MODE 1: conv res (+prev)
// MODE 2: fusion + per-slice max + IN-BLOCK gcon dot (writes gcon; exW = W_p1)
// MODE 3: p1 (+gcon)
// MODE 4: p2 + FUSED p3 (writes final output; exW = W_p3, exB = b_p3)
template<int KTOT, int BN, int WM, int PH, int MODE>
__global__ __launch_bounds__(512) void mgemm8(
    const us* __restrict__ Ah, const us* __restrict__ Al, int lda,
    const us* __restrict__ Bh, const us* __restrict__ Bl,
    const float* __restrict__ bias,
    float* __restrict__ outf, us* __restrict__ outh, us* __restrict__ outl,
    int ldo, int colOff,
    const us* __restrict__ prevh, const us* __restrict__ prevl,
    const float* __restrict__ gcon,
    const float* __restrict__ exW, const float* __restrict__ exB) {
  constexpr int WN  = 8 / WM;
  constexpr int FM  = 16 / WM;
  constexpr int FMP = FM / PH;
  constexpr int NT  = KTOT / 32;
  constexpr int LBN = (BN == 256) ? 8 : ((BN == 128) ? 7 : 6);
  constexpr int CHT = 2048 + BN * 8;
  constexpr int LPT = CHT / 512;

  __shared__ __align__(16) us L[2][CHT * 8];

  const int t = threadIdx.x;
  const int mbase = blockIdx.x * 256;

  const us* gp[LPT];
#pragma unroll
  for (int i = 0; i < LPT; ++i) {
    int id = i * 512 + t;
    if (id < 1024) {
      int row = id & 255, kb = id >> 8;
      gp[i] = Ah + (size_t)(mbase + row) * lda + kb * 8;
    } else if (id < 2048) {
      int c = id - 1024, row = c & 255, kb = c >> 8;
      gp[i] = Al + (size_t)(mbase + row) * lda + kb * 8;
    } else if (id < 2048 + BN * 4) {
      int c = id - 2048, row = c & (BN - 1), kb = c >> LBN;
      gp[i] = Bh + (size_t)row * KTOT + kb * 8;
    } else {
      int c = id - 2048 - BN * 4, row = c & (BN - 1), kb = c >> LBN;
      gp[i] = Bl + (size_t)row * KTOT + kb * 8;
    }
  }

  const int lane = t & 63, wvi = t >> 6;
  const int wm = wvi & (WM - 1), wn = wvi / WM;
  const int l15 = lane & 15, lkb = lane >> 4;
  const int wrow = wm * (256 / WM);

  f32x4 acc[FM][4];
#pragma unroll
  for (int i = 0; i < FM; ++i)
#pragma unroll
    for (int j = 0; j < 4; ++j)
#pragma unroll
      for (int e = 0; e < 4; ++e) acc[i][j][e] = 0.f;

  auto stage = [&](us* Lb, int k0) {
#pragma unroll
    for (int i = 0; i < LPT; ++i)
      gload16(gp[i] + k0, Lb + (size_t)(i * 512 + t) * 8);
  };
  auto waitL = [&]() {
    if constexpr (LPT == 8)      asm volatile("s_waitcnt vmcnt(8)" ::: "memory");
    else if constexpr (LPT == 6) asm volatile("s_waitcnt vmcnt(6)" ::: "memory");
    else                         asm volatile("s_waitcnt vmcnt(5)" ::: "memory");
    __builtin_amdgcn_sched_barrier(0);
  };
  auto wait0 = [&]() {
    asm volatile("s_waitcnt vmcnt(0)" ::: "memory");
    __builtin_amdgcn_sched_barrier(0);
  };
  auto bar = [&]() {
    __builtin_amdgcn_s_barrier();
    __builtin_amdgcn_sched_barrier(0);
  };
  auto ktile = [&](const us* Lb) {
    short8 bh[4], bl[4];
#pragma unroll
    for (int fn = 0; fn < 4; ++fn) {
      const int bcol = wn * 64 + fn * 16 + l15;
      bh[fn] = *(const short8*)(Lb + ((size_t)(2048 + lkb * BN + bcol)) * 8);
      bl[fn] = *(const short8*)(Lb + ((size_t)(2048 + BN * 4 + lkb * BN + bcol)) * 8);
    }
#pragma unroll
    for (int p = 0; p < PH; ++p) {
      short8 ah[FMP], al[FMP];
#pragma unroll
      for (int f = 0; f < FMP; ++f) {
        const int arow = wrow + (p * FMP + f) * 16 + l15;
        ah[f] = *(const short8*)(Lb + ((size_t)(lkb * 256 + arow)) * 8);
        al[f] = *(const short8*)(Lb + ((size_t)(1024 + lkb * 256 + arow)) * 8);
      }
      __builtin_amdgcn_s_setprio(1);
#pragma unroll
      for (int f = 0; f < FMP; ++f)
#pragma unroll
        for (int fn = 0; fn < 4; ++fn)
          acc[p * FMP + f][fn] =
              __builtin_amdgcn_mfma_f32_16x16x32_bf16(ah[f], bh[fn], acc[p * FMP + f][fn], 0, 0, 0);
#pragma unroll
      for (int f = 0; f < FMP; ++f)
#pragma unroll
        for (int fn = 0; fn < 4; ++fn)
          acc[p * FMP + f][fn] =
              __builtin_amdgcn_mfma_f32_16x16x32_bf16(al[f], bh[fn], acc[p * FMP + f][fn], 0, 0, 0);
#pragma unroll
      for (int f = 0; f < FMP; ++f)
#pragma unroll
        for (int fn = 0; fn < 4; ++fn)
          acc[p * FMP + f][fn] =
              __builtin_amdgcn_mfma_f32_16x16x32_bf16(ah[f], bl[fn], acc[p * FMP + f][fn], 0, 0, 0);
      __builtin_amdgcn_s_setprio(0);
      __builtin_amdgcn_sched_barrier(0);
    }
  };

  stage(L[0], 0);
  if (NT > 1) stage(L[1], 32);
#pragma unroll 1
  for (int kt = 0; kt < NT; kt += 2) {
    waitL();
    bar();
    ktile(L[0]);
    bar();
    if (kt + 2 < NT) stage(L[0], (kt + 2) * 32);
    if (kt + 3 < NT) waitL(); else wait0();
    bar();
    ktile(L[1]);
    bar();
    if (kt + 3 < NT) stage(L[1], (kt + 3) * 32);
  }

  if constexpr (MODE == 0 || MODE == 1 || MODE == 3) {
    const float* gc = (MODE == 3) ? (gcon + (size_t)(blockIdx.x * 2 + wm) * 256) : nullptr;
#pragma unroll
    for (int fm = 0; fm < FM; ++fm)
#pragma unroll
      for (int fn = 0; fn < 4; ++fn) {
        const int col = wn * 64 + fn * 16 + l15;
        float bb = bias[col];
        if constexpr (MODE == 3) bb += gc[col];
#pragma unroll
        for (int r = 0; r < 4; ++r) {
          const int row = mbase + wrow + fm * 16 + lkb * 4 + r;
          float v = leaky(acc[fm][fn][r] + bb);
          const size_t off = (size_t)row * ldo + colOff + col;
          if constexpr (MODE == 1) v += b2f(prevh[off - 128]) + b2f(prevl[off - 128]);
          us hi, lo; split2(v, hi, lo);
          outh[off] = hi;
          outl[off] = lo;
        }
      }
  } else if constexpr (MODE == 2) {
    // per-slice max (+bias) into LDS, then in-block gcon dot; writes gcon only.
    __shared__ float gm[2][256];
#pragma unroll
    for (int fn = 0; fn < 4; ++fn) {
      float m = acc[0][fn][0];
#pragma unroll
      for (int fm = 0; fm < FM; ++fm)
#pragma unroll
        for (int r = 0; r < 4; ++r) m = fmaxf(m, acc[fm][fn][r]);
      m = fmaxf(m, __shfl_xor(m, 16));
      m = fmaxf(m, __shfl_xor(m, 32));
      if (lane < 16) {
        const int col = wn * 64 + fn * 16 + l15;
        gm[wm][col] = m + bias[col];
      }
    }
    __syncthreads();
    {
      const int s = t >> 8, o = t & 255;       // 512 threads -> 2 slices x 256 outs
      const float* wr = exW + (size_t)o * 768; // W_p1 global-state cols 0..255
      float sdot = 0.f;
#pragma unroll 4
      for (int c = 0; c < 256; c += 4) {
        float4 w4 = *(const float4*)(wr + c);
        sdot += gm[s][c] * w4.x + gm[s][c + 1] * w4.y + gm[s][c + 2] * w4.z + gm[s][c + 3] * w4.w;
      }
      outf[(size_t)(blockIdx.x * 2 + s) * 256 + o] = sdot;
    }
  } else {  // MODE 4: p2 + fused p3 (WM=8, BN=64) -> final output
    const float b30 = exB[0], b31 = exB[1];
    float w0v[4], w1v[4];
#pragma unroll
    for (int fn = 0; fn < 4; ++fn) {
      w0v[fn] = exW[fn * 16 + l15];
      w1v[fn] = exW[64 + fn * 16 + l15];
    }
#pragma unroll
    for (int fm = 0; fm < FM; ++fm)
#pragma unroll
      for (int r = 0; r < 4; ++r) {
        float p0 = 0.f, p1 = 0.f;
#pragma unroll
        for (int fn = 0; fn < 4; ++fn) {
          const float v = leaky(acc[fm][fn][r] + bias[fn * 16 + l15]);
          p0 = fmaf(v, w0v[fn], p0);
          p1 = fmaf(v, w1v[fn], p1);
        }
        p0 += __shfl_xor(p0, 1); p1 += __shfl_xor(p1, 1);
        p0 += __shfl_xor(p0, 2); p1 += __shfl_xor(p1, 2);
        p0 += __shfl_xor(p0, 4); p1 += __shfl_xor(p1, 4);
        p0 += __shfl_xor(p0, 8); p1 += __shfl_xor(p1, 8);
        if (l15 == 0) {
          const int row = mbase + wrow + fm * 16 + lkb * 4 + r;
          const int s = row >> 7, vv = row & 127;
          outf[((size_t)s * 2 + 0) * 128 + vv] = b30 + p0;
          outf[((size_t)s * 2 + 1) * 128 + vv] = b31 + p1;
        }
      }
  }
}

extern "C" void kernel_launch(void* const* d_in, const int* in_sizes, int n_in,
                              void* d_out, int out_size, void* d_ws, size_t ws_size,
                              hipStream_t stream) {
  const float* x        = (const float*)d_in[0];
  const int*   esrc     = (const int*)d_in[1];
  const int*   edst     = (const int*)d_in[2];
  const float* W_head   = (const float*)d_in[3];
  const float* b_head   = (const float*)d_in[4];
  const float* W_res[3] = {(const float*)d_in[5], (const float*)d_in[7], (const float*)d_in[9]};
  const float* b_res[3] = {(const float*)d_in[6], (const float*)d_in[8], (const float*)d_in[10]};
  const float* W_fusion = (const float*)d_in[11];
  const float* b_fusion = (const float*)d_in[12];
  const float* W_p1     = (const float*)d_in[13];
  const float* b_p1     = (const float*)d_in[14];
  const float* W_p2     = (const float*)d_in[15];
  const float* b_p2     = (const float*)d_in[16];
  const float* W_p3     = (const float*)d_in[17];
  const float* b_p3     = (const float*)d_in[18];
  float* outp = (float*)d_out;

  char* w = (char*)d_ws;
  size_t off = 0;
  auto alloc = [&](size_t bytes) { char* p = w + off; off += (bytes + 255) & ~(size_t)255; return p; };

  us* states_h = (us*)alloc((size_t)NN * 512 * 2);
  us* states_l = (us*)alloc((size_t)NN * 512 * 2);
  char* regionA = alloc((size_t)NN * 128 * 2 * 4);   // h0h|h0l|aggh|aggl, later y1h|y1l
  us* h0h  = (us*)regionA;
  us* h0l  = (us*)(regionA + (size_t)NN * 128 * 2);
  us* aggh = (us*)(regionA + (size_t)NN * 128 * 4);
  us* aggl = (us*)(regionA + (size_t)NN * 128 * 6);
  us* y1h  = (us*)regionA;
  us* y1l  = (us*)(regionA + (size_t)NN * 256 * 2);

  float* gcon   = (float*)alloc(512 * 256 * 4);
  float* rs_out = (float*)alloc((size_t)NN * 4);
  float* rs_in  = (float*)alloc((size_t)NN * 4);
  us* cWh[4]; us* cWl[4];
  for (int l = 0; l < 4; ++l) { cWh[l] = (us*)alloc(128 * 128 * 2); cWl[l] = (us*)alloc(128 * 128 * 2); }
  us* fWh  = (us*)alloc(256 * 512 * 2);
  us* fWl  = (us*)alloc(256 * 512 * 2);
  us* p1Wh = (us*)alloc(256 * 512 * 2);
  us* p1Wl = (us*)alloc(256 * 512 * 2);
  us* p2Wh = (us*)alloc(64 * 256 * 2);
  us* p2Wl = (us*)alloc(64 * 256 * 2);
  int* cnt_out = (int*)alloc((size_t)NN * 4);
  int* cnt_in  = (int*)alloc((size_t)NN * 4);
  int* cursor  = (int*)alloc((size_t)NN * 4);
  int* row_ptr = (int*)alloc(((size_t)NN + 1) * 4);
  int* csr     = (int*)alloc((size_t)NE * 4);

  zero_ints<<<(3 * NN + 255) / 256, 256, 0, stream>>>(cnt_out, 3 * NN);
  deg_count<<<NE / 256, 256, 0, stream>>>(esrc, edst, cnt_out, cnt_in);
  rs_kernel<<<NN / 256, 256, 0, stream>>>(cnt_out, cnt_in, rs_out, rs_in);
  scan_kernel<<<1, 1024, 0, stream>>>(cnt_in, row_ptr);
  csr_fill<<<NE / 256, 256, 0, stream>>>(esrc, edst, row_ptr, cursor, csr);

  transpose_x<<<1024, 256, 0, stream>>>(x, h0h, h0l);
  const float* cW[4] = {W_head, W_res[0], W_res[1], W_res[2]};
  for (int l = 0; l < 4; ++l)
    wsplit_t<<<64, 256, 0, stream>>>(cW[l], cWh[l], cWl[l], 128, 128, 128);
  wsplit<<<512, 256, 0, stream>>>(W_fusion, fWh, fWl, 256, 512, 512, 0);
  wsplit<<<512, 256, 0, stream>>>(W_p1, p1Wh, p1Wl, 256, 512, 768, 256);
  wsplit<<<64, 256, 0, stream>>>(W_p2, p2Wh, p2Wl, 64, 256, 256, 0);

  const float* cB[4] = {b_head, b_res[0], b_res[1], b_res[2]};
  // layer 1 (head)
  aggregate<<<NN / 8, 256, 0, stream>>>(h0h, h0l, 128, row_ptr, csr, rs_out, rs_in, aggh, aggl);
  mgemm8<128, 128, 4, 2, 0><<<256, 512, 0, stream>>>(aggh, aggl, 128, cWh[0], cWl[0], cB[0],
                                                     nullptr, states_h, states_l, 512, 0,
                                                     nullptr, nullptr, nullptr, nullptr, nullptr);
  // layers 2..4 (residual)
  for (int l = 1; l <= 3; ++l) {
    aggregate<<<NN / 8, 256, 0, stream>>>(states_h + (size_t)(l - 1) * 128,
                                          states_l + (size_t)(l - 1) * 128, 512,
                                          row_ptr, csr, rs_out, rs_in, aggh, aggl);
    mgemm8<128, 128, 4, 2, 1><<<256, 512, 0, stream>>>(aggh, aggl, 128, cWh[l], cWl[l], cB[l],
                                                       nullptr, states_h, states_l, 512, l * 128,
                                                       states_h, states_l, nullptr, nullptr, nullptr);
  }
  // fusion conv + per-slice max + in-block gcon -> gcon
  mgemm8<512, 256, 2, 4, 2><<<256, 512, 0, stream>>>(states_h, states_l, 512, fWh, fWl, b_fusion,
                                                     gcon, nullptr, nullptr, 0, 0,
                                                     nullptr, nullptr, nullptr, W_p1, nullptr);
  // p1 -> y1 planes
  mgemm8<512, 256, 2, 4, 3><<<256, 512, 0, stream>>>(states_h, states_l, 512, p1Wh, p1Wl, b_p1,
                                                     nullptr, y1h, y1l, 256, 0,
                                                     nullptr, nullptr, gcon, nullptr, nullptr);
  // p2 + fused p3 -> final output
  mgemm8<256, 64, 8, 2, 4><<<256, 512, 0, stream>>>(y1h, y1l, 256, p2Wh, p2Wl, b_p2,
                                                    outp, nullptr, nullptr, 0, 0,
                                                    nullptr, nullptr, nullptr, W_p3, b_p3);
}

// Round 15
// 587.838 us; speedup vs baseline: 1.4533x; 1.0005x over previous
//
#include <hip/hip_runtime.h>

#define NN 65536
#define NE 524288
#define SLOPE 0.01f

typedef unsigned short us;
typedef __attribute__((ext_vector_type(8))) short short8;
typedef __attribute__((ext_vector_type(16))) float f32x16;

__device__ __forceinline__ float leaky(float v) { return v >= 0.f ? v : SLOPE * v; }
__device__ __forceinline__ float b2f(us u) { return __uint_as_float(((unsigned)u) << 16); }
__device__ __forceinline__ us f2b(float f) {
  unsigned u = __float_as_uint(f);
  u += 0x7fffu + ((u >> 16) & 1u);
  return (us)(u >> 16);
}
__device__ __forceinline__ void split2(float v, us& hi, us& lo) {
  hi = f2b(v);
  lo = f2b(v - b2f(hi));
}

__device__ __forceinline__ void gload16(const void* g, void* l) {
  __builtin_amdgcn_global_load_lds(
      (const __attribute__((address_space(1))) unsigned int*)g,
      (__attribute__((address_space(3))) unsigned int*)l, 16, 0, 0);
}

// ---------------- graph preprocessing ----------------
__global__ void zero_ints(int* __restrict__ p, int n) {
  int i = blockIdx.x * blockDim.x + threadIdx.x;
  if (i < n) p[i] = 0;
}

__global__ void deg_count(const int* __restrict__ src, const int* __restrict__ dst,
                          int* __restrict__ cout, int* __restrict__ cin) {
  int e = blockIdx.x * blockDim.x + threadIdx.x;
  if (e < NE) {
    atomicAdd(&cout[src[e]], 1);
    atomicAdd(&cin[dst[e]], 1);
  }
}

__global__ void rs_kernel(const int* __restrict__ cout, const int* __restrict__ cin,
                          float* __restrict__ rs_out, float* __restrict__ rs_in) {
  int n = blockIdx.x * blockDim.x + threadIdx.x;
  if (n < NN) {
    rs_out[n] = rsqrtf((float)(cout[n] > 0 ? cout[n] : 1));
    rs_in[n]  = rsqrtf((float)(cin[n]  > 0 ? cin[n]  : 1));
  }
}

__global__ __launch_bounds__(1024) void scan_kernel(const int* __restrict__ cnt,
                                                    int* __restrict__ row_ptr) {
  __shared__ int part[1024];
  int t = threadIdx.x;
  int base = t * 64;
  int s = 0;
  for (int i = 0; i < 64; ++i) s += cnt[base + i];
  part[t] = s;
  __syncthreads();
  for (int d = 1; d < 1024; d <<= 1) {
    int v = (t >= d) ? part[t - d] : 0;
    __syncthreads();
    part[t] += v;
    __syncthreads();
  }
  int run = part[t] - s;
  for (int i = 0; i < 64; ++i) { row_ptr[base + i] = run; run += cnt[base + i]; }
  if (t == 1023) row_ptr[NN] = run;
}

__global__ void csr_fill(const int* __restrict__ src, const int* __restrict__ dst,
                         const int* __restrict__ row_ptr, int* __restrict__ cursor,
                         int* __restrict__ csr) {
  int e = blockIdx.x * blockDim.x + threadIdx.x;
  if (e < NE) {
    int d = dst[e];
    int pos = atomicAdd(&cursor[d], 1);
    csr[row_ptr[d] + pos] = src[e];
  }
}

// x [512][128c][128v] -> h0 planes [65536 node][128 c] (hi/lo bf16)
__global__ __launch_bounds__(256) void transpose_x(const float* __restrict__ x,
                                                   us* __restrict__ h0h,
                                                   us* __restrict__ h0l) {
  __shared__ float tile[128][68];
  int s  = blockIdx.x >> 1;
  int vh = (blockIdx.x & 1) * 64;
  const float* xs = x + (size_t)s * 16384;
  int t = threadIdx.x;
  int v4 = t & 15, c0 = t >> 4;
  for (int p = 0; p < 8; ++p) {
    int c = c0 + p * 16;
    float4 val = *(const float4*)(xs + (size_t)c * 128 + vh + v4 * 4);
    *(float4*)&tile[c][v4 * 4] = val;
  }
  __syncthreads();
  int c4 = t & 31, v0 = t >> 5;
  for (int p = 0; p < 8; ++p) {
    int v = v0 + p * 8;
    float o[4];
    o[0] = tile[c4 * 4 + 0][v];
    o[1] = tile[c4 * 4 + 1][v];
    o[2] = tile[c4 * 4 + 2][v];
    o[3] = tile[c4 * 4 + 3][v];
    us hh[4], ll[4];
#pragma unroll
    for (int j = 0; j < 4; ++j) split2(o[j], hh[j], ll[j]);
    size_t off = (size_t)(s * 128 + vh + v) * 128 + c4 * 4;
    uint2 wh = make_uint2((unsigned)hh[0] | ((unsigned)hh[1] << 16),
                          (unsigned)hh[2] | ((unsigned)hh[3] << 16));
    uint2 wl = make_uint2((unsigned)ll[0] | ((unsigned)ll[1] << 16),
                          (unsigned)ll[2] | ((unsigned)ll[3] << 16));
    *(uint2*)(h0h + off) = wh;
    *(uint2*)(h0l + off) = wl;
  }
}

// weight split, fragment-major layout B'[n][k] (src row-major [n][ld], cols koff..)
__global__ void wsplit(const float* __restrict__ src, us* __restrict__ bh,
                       us* __restrict__ bl, int N, int K, int ld, int koff) {
  int idx = blockIdx.x * 256 + threadIdx.x;
  if (idx >= N * K) return;
  int n = idx / K, k = idx - n * K;
  float v = src[(size_t)n * ld + koff + k];
  us hi, lo; split2(v, hi, lo);
  bh[idx] = hi; bl[idx] = lo;
}

// weight split transposed: B'[n][k] = src[k*ld + n]   (conv weights W[k_in][n_out])
__global__ void wsplit_t(const float* __restrict__ src, us* __restrict__ bh,
                         us* __restrict__ bl, int N, int K, int ld) {
  int idx = blockIdx.x * 256 + threadIdx.x;
  if (idx >= N * K) return;
  int n = idx / K, k = idx - n * K;
  float v = src[(size_t)k * ld + n];
  us hi, lo; split2(v, hi, lo);
  bh[idx] = hi; bl[idx] = lo;
}

// aggregate: 2 nodes/wave, 16 B/lane, 4-edge unroll.
__global__ __launch_bounds__(256) void aggregate(
    const us* __restrict__ hh, const us* __restrict__ hl, int lda,
    const int* __restrict__ row_ptr, const int* __restrict__ csr,
    const float* __restrict__ rs_out, const float* __restrict__ rs_in,
    us* __restrict__ aggh, us* __restrict__ aggl) {
  const int lane = threadIdx.x & 63;
  const int wid = threadIdx.x >> 6;
  const int half = (lane >> 5) & 1;
  const int n = blockIdx.x * 8 + wid * 2 + half;
  const bool lop = (lane & 31) >= 16;
  const int c16 = lane & 15;
  const us* base = (lop ? hl : hh) + (size_t)c16 * 8;
  const int b = row_ptr[n], e = row_ptr[n + 1];
  float a[8];
#pragma unroll
  for (int j = 0; j < 8; ++j) a[j] = 0.f;
  int i = b;
  for (; i + 4 <= e; i += 4) {
    int s0 = csr[i], s1 = csr[i + 1], s2 = csr[i + 2], s3 = csr[i + 3];
    uint4 v0 = *(const uint4*)(base + (size_t)s0 * lda);
    uint4 v1 = *(const uint4*)(base + (size_t)s1 * lda);
    uint4 v2 = *(const uint4*)(base + (size_t)s2 * lda);
    uint4 v3 = *(const uint4*)(base + (size_t)s3 * lda);
    float w0 = rs_out[s0], w1 = rs_out[s1], w2 = rs_out[s2], w3 = rs_out[s3];
    a[0] = fmaf(w0, __uint_as_float(v0.x << 16), a[0]);
    a[1] = fmaf(w0, __uint_as_float(v0.x & 0xffff0000u), a[1]);
    a[2] = fmaf(w0, __uint_as_float(v0.y << 16), a[2]);
    a[3] = fmaf(w0, __uint_as_float(v0.y & 0xffff0000u), a[3]);
    a[4] = fmaf(w0, __uint_as_float(v0.z << 16), a[4]);
    a[5] = fmaf(w0, __uint_as_float(v0.z & 0xffff0000u), a[5]);
    a[6] = fmaf(w0, __uint_as_float(v0.w << 16), a[6]);
    a[7] = fmaf(w0, __uint_as_float(v0.w & 0xffff0000u), a[7]);
    a[0] = fmaf(w1, __uint_as_float(v1.x << 16), a[0]);
    a[1] = fmaf(w1, __uint_as_float(v1.x & 0xffff0000u), a[1]);
    a[2] = fmaf(w1, __uint_as_float(v1.y << 16), a[2]);
    a[3] = fmaf(w1, __uint_as_float(v1.y & 0xffff0000u), a[3]);
    a[4] = fmaf(w1, __uint_as_float(v1.z << 16), a[4]);
    a[5] = fmaf(w1, __uint_as_float(v1.z & 0xffff0000u), a[5]);
    a[6] = fmaf(w1, __uint_as_float(v1.w << 16), a[6]);
    a[7] = fmaf(w1, __uint_as_float(v1.w & 0xffff0000u), a[7]);
    a[0] = fmaf(w2, __uint_as_float(v2.x << 16), a[0]);
    a[1] = fmaf(w2, __uint_as_float(v2.x & 0xffff0000u), a[1]);
    a[2] = fmaf(w2, __uint_as_float(v2.y << 16), a[2]);
    a[3] = fmaf(w2, __uint_as_float(v2.y & 0xffff0000u), a[3]);
    a[4] = fmaf(w2, __uint_as_float(v2.z << 16), a[4]);
    a[5] = fmaf(w2, __uint_as_float(v2.z & 0xffff0000u), a[5]);
    a[6] = fmaf(w2, __uint_as_float(v2.w << 16), a[6]);
    a[7] = fmaf(w2, __uint_as_float(v2.w & 0xffff0000u), a[7]);
    a[0] = fmaf(w3, __uint_as_float(v3.x << 16), a[0]);
    a[1] = fmaf(w3, __uint_as_float(v3.x & 0xffff0000u), a[1]);
    a[2] = fmaf(w3, __uint_as_float(v3.y << 16), a[2]);
    a[3] = fmaf(w3, __uint_as_float(v3.y & 0xffff0000u), a[3]);
    a[4] = fmaf(w3, __uint_as_float(v3.z << 16), a[4]);
    a[5] = fmaf(w3, __uint_as_float(v3.z & 0xffff0000u), a[5]);
    a[6] = fmaf(w3, __uint_as_float(v3.w << 16), a[6]);
    a[7] = fmaf(w3, __uint_as_float(v3.w & 0xffff0000u), a[7]);
  }
  for (; i < e; ++i) {
    int s0 = csr[i];
    uint4 v0 = *(const uint4*)(base + (size_t)s0 * lda);
    float w0 = rs_out[s0];
    a[0] = fmaf(w0, __uint_as_float(v0.x << 16), a[0]);
    a[1] = fmaf(w0, __uint_as_float(v0.x & 0xffff0000u), a[1]);
    a[2] = fmaf(w0, __uint_as_float(v0.y << 16), a[2]);
    a[3] = fmaf(w0, __uint_as_float(v0.y & 0xffff0000u), a[3]);
    a[4] = fmaf(w0, __uint_as_float(v0.z << 16), a[4]);
    a[5] = fmaf(w0, __uint_as_float(v0.z & 0xffff0000u), a[5]);
    a[6] = fmaf(w0, __uint_as_float(v0.w << 16), a[6]);
    a[7] = fmaf(w0, __uint_as_float(v0.w & 0xffff0000u), a[7]);
  }
#pragma unroll
  for (int j = 0; j < 8; ++j) a[j] += __shfl_xor(a[j], 16);
  const float ri = rs_in[n];
  us h8[8], l8[8];
#pragma unroll
  for (int j = 0; j < 8; ++j) split2(a[j] * ri, h8[j], l8[j]);
  size_t o = (size_t)n * 128 + (size_t)c16 * 8;
  if (!lop) {
    uint4 w = make_uint4((unsigned)h8[0] | ((unsigned)h8[1] << 16),
                         (unsigned)h8[2] | ((unsigned)h8[3] << 16),
                         (unsigned)h8[4] | ((unsigned)h8[5] << 16),
                         (unsigned)h8[6] | ((unsigned)h8[7] << 16));
    *(uint4*)(aggh + o) = w;
  } else {
    uint4 w = make_uint4((unsigned)l8[0] | ((unsigned)l8[1] << 16),
                         (unsigned)l8[2] | ((unsigned)l8[3] << 16),
                         (unsigned)l8[4] | ((unsigned)l8[5] << 16),
                         (unsigned)l8[6] | ((unsigned)l8[7] << 16));
    *(uint4*)(aggl + o) = w;
  }
}

// ---------------- 256-row free-run split-bf16 MFMA GEMM (32x32x16 frags) ----------------
// Per K-tile TWO runtime barriers: waitL(counted vmcnt) -> bar(publish) -> free-run
// ktile (2 phases of s=k-step; sched_barrier-fenced) -> bar(readers done) -> restage.
// 32x32x16: A lane l holds row l&31, k=(l>>5)*8+j; C/D col=lane&31,
// row=(reg&3)+8*(reg>>2)+4*(lane>>5)   [HW-verified, R2 end-to-end].
// Wave grid: WM x (8/WM); wave tile (256/WM) x 64 cols. FM32=(256/WM)/32, FN32=2.
// MODE 0: conv head  MODE 1: conv res (+prev)
// MODE 2: fusion + per-slice max + IN-BLOCK gcon dot (writes gcon; exW = W_p1)  [WM=2]
// MODE 3: p1 (+gcon)  [WM=2]
// MODE 4: p2 + FUSED p3 (writes final output; exW = W_p3, exB = b_p3)  [WM=8]
template<int KTOT, int BN, int WM, int MODE>
__global__ __launch_bounds__(512) void mgemm8(
    const us* __restrict__ Ah, const us* __restrict__ Al, int lda,
    const us* __restrict__ Bh, const us* __restrict__ Bl,
    const float* __restrict__ bias,
    float* __restrict__ outf, us* __restrict__ outh, us* __restrict__ outl,
    int ldo, int colOff,
    const us* __restrict__ prevh, const us* __restrict__ prevl,
    const float* __restrict__ gcon,
    const float* __restrict__ exW, const float* __restrict__ exB) {
  constexpr int FM  = (256 / WM) / 32;    // 4 (WM=2), 2 (WM=4), 1 (WM=8)
  constexpr int NT  = KTOT / 32;
  constexpr int LBN = (BN == 256) ? 8 : ((BN == 128) ? 7 : 6);
  constexpr int CHT = 2048 + BN * 8;
  constexpr int LPT = CHT / 512;

  __shared__ __align__(16) us L[2][CHT * 8];

  const int t = threadIdx.x;
  const int mbase = blockIdx.x * 256;

  const us* gp[LPT];
#pragma unroll
  for (int i = 0; i < LPT; ++i) {
    int id = i * 512 + t;
    if (id < 1024) {
      int row = id & 255, kb = id >> 8;
      gp[i] = Ah + (size_t)(mbase + row) * lda + kb * 8;
    } else if (id < 2048) {
      int c = id - 1024, row = c & 255, kb = c >> 8;
      gp[i] = Al + (size_t)(mbase + row) * lda + kb * 8;
    } else if (id < 2048 + BN * 4) {
      int c = id - 2048, row = c & (BN - 1), kb = c >> LBN;
      gp[i] = Bh + (size_t)row * KTOT + kb * 8;
    } else {
      int c = id - 2048 - BN * 4, row = c & (BN - 1), kb = c >> LBN;
      gp[i] = Bl + (size_t)row * KTOT + kb * 8;
    }
  }

  const int lane = t & 63, wvi = t >> 6;
  const int wm = wvi & (WM - 1), wn = wvi / WM;
  const int l31 = lane & 31, lh2 = lane >> 5;
  const int wrow = wm * (256 / WM);

  f32x16 acc[FM][2];
#pragma unroll
  for (int i = 0; i < FM; ++i)
#pragma unroll
    for (int j = 0; j < 2; ++j)
#pragma unroll
      for (int e = 0; e < 16; ++e) acc[i][j][e] = 0.f;

  auto stage = [&](us* Lb, int k0) {
#pragma unroll
    for (int i = 0; i < LPT; ++i)
      gload16(gp[i] + k0, Lb + (size_t)(i * 512 + t) * 8);
  };
  auto waitL = [&]() {
    if constexpr (LPT == 8)      asm volatile("s_waitcnt vmcnt(8)" ::: "memory");
    else if constexpr (LPT == 6) asm volatile("s_waitcnt vmcnt(6)" ::: "memory");
    else                         asm volatile("s_waitcnt vmcnt(5)" ::: "memory");
    __builtin_amdgcn_sched_barrier(0);
  };
  auto wait0 = [&]() {
    asm volatile("s_waitcnt vmcnt(0)" ::: "memory");
    __builtin_amdgcn_sched_barrier(0);
  };
  auto bar = [&]() {
    __builtin_amdgcn_s_barrier();
    __builtin_amdgcn_sched_barrier(0);
  };
  // K-tile = 2 k-steps (s=0,1) of K=16. Per step: kb = 2*s + lh2.
  auto ktile = [&](const us* Lb) {
#pragma unroll
    for (int s = 0; s < 2; ++s) {
      const int kb = 2 * s + lh2;
      short8 bh[2], bl[2], ah[FM], al[FM];
#pragma unroll
      for (int fn = 0; fn < 2; ++fn) {
        const int bcol = wn * 64 + fn * 32 + l31;
        bh[fn] = *(const short8*)(Lb + ((size_t)(2048 + kb * BN + bcol)) * 8);
        bl[fn] = *(const short8*)(Lb + ((size_t)(2048 + BN * 4 + kb * BN + bcol)) * 8);
      }
#pragma unroll
      for (int f = 0; f < FM; ++f) {
        const int arow = wrow + f * 32 + l31;
        ah[f] = *(const short8*)(Lb + ((size_t)(kb * 256 + arow)) * 8);
        al[f] = *(const short8*)(Lb + ((size_t)(1024 + kb * 256 + arow)) * 8);
      }
      __builtin_amdgcn_s_setprio(1);
#pragma unroll
      for (int f = 0; f < FM; ++f)
#pragma unroll
        for (int fn = 0; fn < 2; ++fn)
          acc[f][fn] = __builtin_amdgcn_mfma_f32_32x32x16_bf16(ah[f], bh[fn], acc[f][fn], 0, 0, 0);
#pragma unroll
      for (int f = 0; f < FM; ++f)
#pragma unroll
        for (int fn = 0; fn < 2; ++fn)
          acc[f][fn] = __builtin_amdgcn_mfma_f32_32x32x16_bf16(al[f], bh[fn], acc[f][fn], 0, 0, 0);
#pragma unroll
      for (int f = 0; f < FM; ++f)
#pragma unroll
        for (int fn = 0; fn < 2; ++fn)
          acc[f][fn] = __builtin_amdgcn_mfma_f32_32x32x16_bf16(ah[f], bl[fn], acc[f][fn], 0, 0, 0);
      __builtin_amdgcn_s_setprio(0);
      __builtin_amdgcn_sched_barrier(0);
    }
  };

  stage(L[0], 0);
  if (NT > 1) stage(L[1], 32);
#pragma unroll 1
  for (int kt = 0; kt < NT; kt += 2) {
    waitL();
    bar();
    ktile(L[0]);
    bar();
    if (kt + 2 < NT) stage(L[0], (kt + 2) * 32);
    if (kt + 3 < NT) waitL(); else wait0();
    bar();
    ktile(L[1]);
    bar();
    if (kt + 3 < NT) stage(L[1], (kt + 3) * 32);
  }

  // C/D: col = lane&31, row = (reg&3) + 8*(reg>>2) + 4*(lane>>5)
  if constexpr (MODE == 0 || MODE == 1 || MODE == 3) {
    const float* gc = (MODE == 3) ? (gcon + (size_t)(blockIdx.x * 2 + wm) * 256) : nullptr;
#pragma unroll
    for (int fm = 0; fm < FM; ++fm)
#pragma unroll
      for (int fn = 0; fn < 2; ++fn) {
        const int col = wn * 64 + fn * 32 + l31;
        float bb = bias[col];
        if constexpr (MODE == 3) bb += gc[col];
#pragma unroll
        for (int r = 0; r < 16; ++r) {
          const int row = mbase + wrow + fm * 32 + (r & 3) + 8 * (r >> 2) + 4 * lh2;
          float v = leaky(acc[fm][fn][r] + bb);
          const size_t off = (size_t)row * ldo + colOff + col;
          if constexpr (MODE == 1) v += b2f(prevh[off - 128]) + b2f(prevl[off - 128]);
          us hi, lo; split2(v, hi, lo);
          outh[off] = hi;
          outl[off] = lo;
        }
      }
  } else if constexpr (MODE == 2) {
    // WM=2: wave tile 128 rows = slice blockIdx*2+wm. Per-col max + in-block gcon.
    __shared__ float gm[2][256];
#pragma unroll
    for (int fn = 0; fn < 2; ++fn) {
      float m = acc[0][fn][0];
#pragma unroll
      for (int fm = 0; fm < FM; ++fm)
#pragma unroll
        for (int r = 0; r < 16; ++r) m = fmaxf(m, acc[fm][fn][r]);
      m = fmaxf(m, __shfl_xor(m, 32));
      if (lane < 32) {
        const int col = wn * 64 + fn * 32 + l31;
        gm[wm][col] = m + bias[col];
      }
    }
    __syncthreads();
    {
      const int s = t >> 8, o = t & 255;       // 512 threads -> 2 slices x 256 outs
      const float* wr = exW + (size_t)o * 768; // W_p1 global-state cols 0..255
      float sdot = 0.f;
#pragma unroll 4
      for (int c = 0; c < 256; c += 4) {
        float4 w4 = *(const float4*)(wr + c);
        sdot += gm[s][c] * w4.x + gm[s][c + 1] * w4.y + gm[s][c + 2] * w4.z + gm[s][c + 3] * w4.w;
      }
      outf[(size_t)(blockIdx.x * 2 + s) * 256 + o] = sdot;
    }
  } else {  // MODE 4: p2 + fused p3 (WM=8, BN=64, FM=1) -> final output
    const float b30 = exB[0], b31 = exB[1];
    float w0v[2], w1v[2];
#pragma unroll
    for (int fn = 0; fn < 2; ++fn) {
      w0v[fn] = exW[fn * 32 + l31];
      w1v[fn] = exW[64 + fn * 32 + l31];
    }
#pragma unroll
    for (int r = 0; r < 16; ++r) {
      float p0 = 0.f, p1 = 0.f;
#pragma unroll
      for (int fn = 0; fn < 2; ++fn) {
        const float v = leaky(acc[0][fn][r] + bias[fn * 32 + l31]);
        p0 = fmaf(v, w0v[fn], p0);
        p1 = fmaf(v, w1v[fn], p1);
      }
      p0 += __shfl_xor(p0, 1);  p1 += __shfl_xor(p1, 1);
      p0 += __shfl_xor(p0, 2);  p1 += __shfl_xor(p1, 2);
      p0 += __shfl_xor(p0, 4);  p1 += __shfl_xor(p1, 4);
      p0 += __shfl_xor(p0, 8);  p1 += __shfl_xor(p1, 8);
      p0 += __shfl_xor(p0, 16); p1 += __shfl_xor(p1, 16);
      if (l31 == 0) {
        const int row = mbase + wrow + (r & 3) + 8 * (r >> 2) + 4 * lh2;
        const int s = row >> 7, vv = row & 127;
        outf[((size_t)s * 2 + 0) * 128 + vv] = b30 + p0;
        outf[((size_t)s * 2 + 1) * 128 + vv] = b31 + p1;
      }
    }
  }
}

extern "C" void kernel_launch(void* const* d_in, const int* in_sizes, int n_in,
                              void* d_out, int out_size, void* d_ws, size_t ws_size,
                              hipStream_t stream) {
  const float* x        = (const float*)d_in[0];
  const int*   esrc     = (const int*)d_in[1];
  const int*   edst     = (const int*)d_in[2];
  const float* W_head   = (const float*)d_in[3];
  const float* b_head   = (const float*)d_in[4];
  const float* W_res[3] = {(const float*)d_in[5], (const float*)d_in[7], (const float*)d_in[9]};
  const float* b_res[3] = {(const float*)d_in[6], (const float*)d_in[8], (const float*)d_in[10]};
  const float* W_fusion = (const float*)d_in[11];
  const float* b_fusion = (const float*)d_in[12];
  const float* W_p1     = (const float*)d_in[13];
  const float* b_p1     = (const float*)d_in[14];
  const float* W_p2     = (const float*)d_in[15];
  const float* b_p2     = (const float*)d_in[16];
  const float* W_p3     = (const float*)d_in[17];
  const float* b_p3     = (const float*)d_in[18];
  float* outp = (float*)d_out;

  char* w = (char*)d_ws;
  size_t off = 0;
  auto alloc = [&](size_t bytes) { char* p = w + off; off += (bytes + 255) & ~(size_t)255; return p; };

  us* states_h = (us*)alloc((size_t)NN * 512 * 2);
  us* states_l = (us*)alloc((size_t)NN * 512 * 2);
  char* regionA = alloc((size_t)NN * 128 * 2 * 4);   // h0h|h0l|aggh|aggl, later y1h|y1l
  us* h0h  = (us*)regionA;
  us* h0l  = (us*)(regionA + (size_t)NN * 128 * 2);
  us* aggh = (us*)(regionA + (size_t)NN * 128 * 4);
  us* aggl = (us*)(regionA + (size_t)NN * 128 * 6);
  us* y1h  = (us*)regionA;
  us* y1l  = (us*)(regionA + (size_t)NN * 256 * 2);

  float* gcon   = (float*)alloc(512 * 256 * 4);
  float* rs_out = (float*)alloc((size_t)NN * 4);
  float* rs_in  = (float*)alloc((size_t)NN * 4);
  us* cWh[4]; us* cWl[4];
  for (int l = 0; l < 4; ++l) { cWh[l] = (us*)alloc(128 * 128 * 2); cWl[l] = (us*)alloc(128 * 128 * 2); }
  us* fWh  = (us*)alloc(256 * 512 * 2);
  us* fWl  = (us*)alloc(256 * 512 * 2);
  us* p1Wh = (us*)alloc(256 * 512 * 2);
  us* p1Wl = (us*)alloc(256 * 512 * 2);
  us* p2Wh = (us*)alloc(64 * 256 * 2);
  us* p2Wl = (us*)alloc(64 * 256 * 2);
  int* cnt_out = (int*)alloc((size_t)NN * 4);
  int* cnt_in  = (int*)alloc((size_t)NN * 4);
  int* cursor  = (int*)alloc((size_t)NN * 4);
  int* row_ptr = (int*)alloc(((size_t)NN + 1) * 4);
  int* csr     = (int*)alloc((size_t)NE * 4);

  zero_ints<<<(3 * NN + 255) / 256, 256, 0, stream>>>(cnt_out, 3 * NN);
  deg_count<<<NE / 256, 256, 0, stream>>>(esrc, edst, cnt_out, cnt_in);
  rs_kernel<<<NN / 256, 256, 0, stream>>>(cnt_out, cnt_in, rs_out, rs_in);
  scan_kernel<<<1, 1024, 0, stream>>>(cnt_in, row_ptr);
  csr_fill<<<NE / 256, 256, 0, stream>>>(esrc, edst, row_ptr, cursor, csr);

  transpose_x<<<1024, 256, 0, stream>>>(x, h0h, h0l);
  const float* cW[4] = {W_head, W_res[0], W_res[1], W_res[2]};
  for (int l = 0; l < 4; ++l)
    wsplit_t<<<64, 256, 0, stream>>>(cW[l], cWh[l], cWl[l], 128, 128, 128);
  wsplit<<<512, 256, 0, stream>>>(W_fusion, fWh, fWl, 256, 512, 512, 0);
  wsplit<<<512, 256, 0, stream>>>(W_p1, p1Wh, p1Wl, 256, 512, 768, 256);
  wsplit<<<64, 256, 0, stream>>>(W_p2, p2Wh, p2Wl, 64, 256, 256, 0);

  const float* cB[4] = {b_head, b_res[0], b_res[1], b_res[2]};
  // layer 1 (head)
  aggregate<<<NN / 8, 256, 0, stream>>>(h0h, h0l, 128, row_ptr, csr, rs_out, rs_in, aggh, aggl);
  mgemm8<128, 128, 4, 0><<<256, 512, 0, stream>>>(aggh, aggl, 128, cWh[0], cWl[0], cB[0],
                                                  nullptr, states_h, states_l, 512, 0,
                                                  nullptr, nullptr, nullptr, nullptr, nullptr);
  // layers 2..4 (residual)
  for (int l = 1; l <= 3; ++l) {
    aggregate<<<NN / 8, 256, 0, stream>>>(states_h + (size_t)(l - 1) * 128,
                                          states_l + (size_t)(l - 1) * 128, 512,
                                          row_ptr, csr, rs_out, rs_in, aggh, aggl);
    mgemm8<128, 128, 4, 1><<<256, 512, 0, stream>>>(aggh, aggl, 128, cWh[l], cWl[l], cB[l],
                                                    nullptr, states_h, states_l, 512, l * 128,
                                                    states_h, states_l, nullptr, nullptr, nullptr);
  }
  // fusion conv + per-slice max + in-block gcon -> gcon
  mgemm8<512, 256, 2, 2><<<256, 512, 0, stream>>>(states_h, states_l, 512, fWh, fWl, b_fusion,
                                                  gcon, nullptr, nullptr, 0, 0,
                                                  nullptr, nullptr, nullptr, W_p1, nullptr);
  // p1 -> y1 planes
  mgemm8<512, 256, 2, 3><<<256, 512, 0, stream>>>(states_h, states_l, 512, p1Wh, p1Wl, b_p1,
                                                  nullptr, y1h, y1l, 256, 0,
                                                  nullptr, nullptr, gcon, nullptr, nullptr);
  // p2 + fused p3 -> final output
  mgemm8<256, 64, 8, 4><<<256, 512, 0, stream>>>(y1h, y1l, 256, p2Wh, p2Wl, b_p2,
                                                 outp, nullptr, nullptr, 0, 0,
                                                 nullptr, nullptr, nullptr, W_p3, b_p3);
}